// Round 16
// baseline (254.703 us; speedup 1.0000x reference)
//
#include <hip/hip_runtime.h>
#include <stdint.h>

typedef unsigned short u16;
typedef __bf16 bf16x8 __attribute__((ext_vector_type(8)));
typedef float  f32x4  __attribute__((ext_vector_type(4)));

// ---- problem constants ----
#define SDIM 2048
#define BDIM 8
#define DIN  1024
#define DOUT 4096
#define EDIM 8
#define RDIM 16
#define KAUG 1152            // DIN + E*R
#define MDIM (SDIM*BDIM)     // 16384
#define SCH  32
#define NT2  18              // K-tiles of 64 for the main GEMM

__device__ __forceinline__ u16 f2bf(float f) {
    __bf16 h = (__bf16)f;
    return __builtin_bit_cast(u16, h);
}

__device__ __forceinline__ void gload16(const u16* g, u16* lds) {
    __builtin_amdgcn_global_load_lds(
        (const __attribute__((address_space(1))) void*)g,
        (__attribute__((address_space(3))) void*)lds, 16, 0, 0);
}

#define VMCNT(n)  asm volatile("s_waitcnt vmcnt(" #n ")" ::: "memory")
#define BARF()    do { asm volatile("" ::: "memory");                \
                       __builtin_amdgcn_s_barrier();                 \
                       asm volatile("" ::: "memory"); } while (0)

// ---------------------------------------------------------------------------
// k1: per-(b, s-chunk) partial sums of x over s + bf16 convert into Xb
// ---------------------------------------------------------------------------
__global__ __launch_bounds__(256) void k1_reduce_convert(
    const float* __restrict__ x, u16* __restrict__ Xb, float* __restrict__ P)
{
    const int b  = blockIdx.x;
    const int sc = blockIdx.y;
    const int i  = threadIdx.x * 4;
    float a0 = 0.f, a1 = 0.f, a2 = 0.f, a3 = 0.f;
    const int s0 = sc * (SDIM / SCH);
    for (int s = s0; s < s0 + (SDIM / SCH); ++s) {
        const float4 v = *reinterpret_cast<const float4*>(
            &x[((size_t)s * BDIM + b) * DIN + i]);
        a0 += v.x; a1 += v.y; a2 += v.z; a3 += v.w;
        ushort4 u{f2bf(v.x), f2bf(v.y), f2bf(v.z), f2bf(v.w)};
        *reinterpret_cast<ushort4*>(&Xb[((size_t)s * BDIM + b) * KAUG + i]) = u;
    }
    float4 p{a0, a1, a2, a3};
    *reinterpret_cast<float4*>(&P[((size_t)sc * BDIM + b) * DIN + i]) = p;
}

// ---------------------------------------------------------------------------
// k2: gate weights
// ---------------------------------------------------------------------------
__global__ __launch_bounds__(256) void k2_gates(
    const float* __restrict__ P, const float* __restrict__ gw,
    const float* __restrict__ gb, float* __restrict__ g)
{
    const int e = blockIdx.x, b = blockIdx.y, t = threadIdx.x;
    float dot = 0.f;
    for (int i = t; i < DIN; i += 256) {
        float xs = 0.f;
        #pragma unroll
        for (int c = 0; c < SCH; ++c) xs += P[((size_t)c * BDIM + b) * DIN + i];
        dot += xs * gw[(size_t)e * DIN + i];
    }
    __shared__ float red[256];
    red[t] = dot;
    __syncthreads();
    #pragma unroll
    for (int off = 128; off > 0; off >>= 1) {
        if (t < off) red[t] += red[t + off];
        __syncthreads();
    }
    if (t == 0) g[b * EDIM + e] = red[0] * (1.0f / SDIM) + gb[e];
}

// ---------------------------------------------------------------------------
// kw: build Waug
// ---------------------------------------------------------------------------
__global__ __launch_bounds__(256) void kw_build_waug(
    const float* __restrict__ W, const float* __restrict__ lb, u16* __restrict__ Waug)
{
    const int o = blockIdx.x, t = threadIdx.x;
    for (int i = t; i < DIN; i += 256)
        Waug[(size_t)o * KAUG + i] = f2bf(W[(size_t)o * DIN + i]);
    if (t < EDIM * RDIM) {
        const int e = t >> 4, r = t & 15;
        Waug[(size_t)o * KAUG + DIN + t] =
            f2bf(lb[((size_t)e * DOUT + o) * RDIM + r]);
    }
}

__global__ __launch_bounds__(256) void kl_convert(
    const float* __restrict__ la, u16* __restrict__ LAb)
{
    const int idx = blockIdx.x * 256 + threadIdx.x;
    if (idx < EDIM * RDIM * DIN) LAb[idx] = f2bf(la[idx]);
}

// ---------------------------------------------------------------------------
// gemm_lora: t = Xb(:, :1024) * LAb^T, fused epilogue u = bf16(g*t) written
// directly into Xb cols [1024,1152). 128x128 tile, BK=64, R6 layout.
// ---------------------------------------------------------------------------
__global__ __launch_bounds__(256) void gemm_lora(
    const u16* __restrict__ A, const u16* __restrict__ B,
    const float* __restrict__ G, u16* __restrict__ Xb)
{
    __shared__ __align__(16) u16 As[128][64];
    __shared__ __align__(16) u16 Bs[128][64];

    const int tid  = threadIdx.x;
    const int lane = tid & 63;
    const int l15  = lane & 15;
    const int l4   = lane >> 4;
    const int sw   = lane & 7;
    const int wid  = tid >> 6;
    const int wr   = wid >> 1;
    const int wc   = wid & 1;
    const int m0 = blockIdx.y * 128;

    f32x4 acc[4][4] = {};

    for (int kt = 0; kt < DIN / 64; ++kt) {
        #pragma unroll
        for (int ii = 0; ii < 4; ++ii) {
            const int cix = ii * 256 + tid;
            const int row = cix >> 3, cl = cix & 7;
            const int kof = kt * 64 + ((cl ^ (row & 7)) << 3);
            gload16(A + (size_t)(m0 + row) * KAUG + kof, &As[0][0] + cix * 8);
            gload16(B + (size_t)row * DIN + kof, &Bs[0][0] + cix * 8);
        }
        __syncthreads();
        #pragma unroll
        for (int ks = 0; ks < 2; ++ks) {
            bf16x8 av[4], bv[4];
            #pragma unroll
            for (int mi = 0; mi < 4; ++mi)
                av[mi] = *reinterpret_cast<const bf16x8*>(
                    &As[wr * 64 + mi * 16 + l15][((ks * 4 + l4) ^ sw) << 3]);
            #pragma unroll
            for (int ni = 0; ni < 4; ++ni)
                bv[ni] = *reinterpret_cast<const bf16x8*>(
                    &Bs[wc * 64 + ni * 16 + l15][((ks * 4 + l4) ^ sw) << 3]);
            #pragma unroll
            for (int mi = 0; mi < 4; ++mi)
                #pragma unroll
                for (int ni = 0; ni < 4; ++ni)
                    acc[mi][ni] = __builtin_amdgcn_mfma_f32_16x16x32_bf16(
                        av[mi], bv[ni], acc[mi][ni], 0, 0, 0);
        }
        __syncthreads();
    }

    #pragma unroll
    for (int mi = 0; mi < 4; ++mi) {
        const int r0 = m0 + wr * 64 + mi * 16 + l4 * 4;
        #pragma unroll
        for (int ni = 0; ni < 4; ++ni) {
            const int col = wc * 64 + ni * 16 + l15;   // 0..127
            const int e   = col >> 4;
            #pragma unroll
            for (int r = 0; r < 4; ++r) {
                const int row = r0 + r;
                const float gv = G[((row & 7) << 3) + e];
                Xb[(size_t)row * KAUG + DIN + col] = f2bf(gv * acc[mi][ni][r]);
            }
        }
    }
}

// ---------------------------------------------------------------------------
// gemm_main R15: MINIMUM-SYNC body — 1 barrier + 1 vmcnt per K-tile.
// Geometry/layout identical to R8 (best): BM=BN=256, BK=64, NT2=18, 512 thr
// (8 waves 2Mx4N), dbuf LDS 128 KiB, coalesced staging + (row&7) chunk-XOR,
// supertile XCD mapping (R12: FETCH 166->110 MB).
//
// Rationale (R8..R14 tally): schedule variants all 170-187us; R14 (less LDS
// traffic) was WORSE -> binder is barrier-lockstep granularity, not the LDS
// port or ordering. This body removes 3 of 4 barriers: waves free-run across
// the whole K-tile, so MFMA of early waves overlaps reads/staging of late
// waves; compiler's counted lgkmcnt pipelines read->MFMA within a wave.
//
// Body j: { VMCNT(0)  [drains stage(j), issued 1 full body (~3000cy) ago ->
//           ~free; guarantees tile j complete in LDS for this wave]
//           BAR       [globalizes: all waves' stage(j) parts landed]
//           stage(j+1) -> buf j^1   [8 gloads]
//           reads tile j (24 x ds_read_b128) ; 64 MFMA  (no sched pinning) }
// WAR: stage(j+1) overwrites buf j^1, whose tile-(j-1) reads were consumed
// by MMA(j-1) BEFORE each wave reached BAR(j) (program order); stages issue
// only after BAR(j). Safe by construction. Tail: j==NT2-1 skips stage.
// ---------------------------------------------------------------------------
__global__ __launch_bounds__(512) void gemm_main(
    const u16* __restrict__ A, const u16* __restrict__ Bm,
    float* __restrict__ C, const float* __restrict__ bias)
{
    __shared__ __align__(16) u16 As[2][2][128][64];   // [buf][Mhalf][row][k] 64 KiB
    __shared__ __align__(16) u16 Bs[2][2][128][64];   // [buf][Nhalf][row][k] 64 KiB

    const int tid  = threadIdx.x;
    const int lane = tid & 63;
    const int l15  = lane & 15;
    const int l4   = lane >> 4;
    const int sw   = lane & 7;
    const int wid  = tid >> 6;      // 0..7
    const int wm   = wid >> 2;      // 0..1  (128-row half)
    const int wn   = wid & 3;       // 0..3  (64-col quarter)
    const int bh   = wn >> 1;       // B Nhalf
    const int bl   = wn & 1;        // 64-row block within half

    // supertile XCD mapping (R12-verified)
    const int f   = blockIdx.x + blockIdx.y * gridDim.x;
    const int xcd = f & 7, k = f >> 3;
    const int gn  = xcd & 3, gm = xcd >> 2;
    const int n0  = (gn * 4 + (k & 3)) * 256;
    const int m0  = (gm * 32 + (k >> 2)) * 256;

    f32x4  acc[8][4] = {};
    bf16x8 aq[2][2], bv[4][2];

    auto stageA = [&](int t, int hf) {
        const int buf = t & 1;
        #pragma unroll
        for (int ii = 0; ii < 2; ++ii) {
            const int cix = ii * 512 + tid;
            const int row = cix >> 3, cl = cix & 7;
            const int kof = t * 64 + ((cl ^ (row & 7)) << 3);
            gload16(A + (size_t)(m0 + hf * 128 + row) * KAUG + kof,
                    &As[buf][hf][0][0] + cix * 8);
        }
    };
    auto stageB = [&](int t, int hf) {
        const int buf = t & 1;
        #pragma unroll
        for (int ii = 0; ii < 2; ++ii) {
            const int cix = ii * 512 + tid;
            const int row = cix >> 3, cl = cix & 7;
            const int kof = t * 64 + ((cl ^ (row & 7)) << 3);
            gload16(Bm + (size_t)(n0 + hf * 128 + row) * KAUG + kof,
                    &Bs[buf][hf][0][0] + cix * 8);
        }
    };

    #define RD_BV(BUF)                                                        \
        _Pragma("unroll") for (int nf = 0; nf < 4; ++nf)                      \
            _Pragma("unroll") for (int kk = 0; kk < 2; ++kk)                  \
                bv[nf][kk] = *reinterpret_cast<const bf16x8*>(                \
                    &Bs[BUF][bh][bl * 64 + nf * 16 + l15]                     \
                       [((kk * 4 + l4) ^ sw) << 3]);
    #define RD_AQ(BUF, Q)                                                     \
        _Pragma("unroll") for (int fr = 0; fr < 2; ++fr)                      \
            _Pragma("unroll") for (int kk = 0; kk < 2; ++kk)                  \
                aq[fr][kk] = *reinterpret_cast<const bf16x8*>(                \
                    &As[BUF][wm][(Q) * 32 + fr * 16 + l15]                    \
                       [((kk * 4 + l4) ^ sw) << 3]);
    #define MMA(Q)                                                            \
        do {                                                                  \
            __builtin_amdgcn_s_setprio(1);                                    \
            _Pragma("unroll") for (int kk = 0; kk < 2; ++kk)                  \
                _Pragma("unroll") for (int fr = 0; fr < 2; ++fr)              \
                    _Pragma("unroll") for (int nf = 0; nf < 4; ++nf)          \
                        acc[(Q) * 2 + fr][nf] =                               \
                            __builtin_amdgcn_mfma_f32_16x16x32_bf16(          \
                                aq[fr][kk], bv[nf][kk],                       \
                                acc[(Q) * 2 + fr][nf], 0, 0, 0);              \
            __builtin_amdgcn_s_setprio(0);                                    \
        } while (0)

    // prologue: stage tile 0 (8 gloads). Body 0's VMCNT(0) gates it.
    stageA(0, 0); stageA(0, 1); stageB(0, 0); stageB(0, 1);

    for (int j = 0; j < NT2; ++j) {
        const int buf = j & 1;
        VMCNT(0);                 // tile j landed (this wave's 8 loads)
        BARF();                   // all waves' parts visible
        if (j + 1 < NT2) {        // prefetch next tile into the other buffer
            stageA(j + 1, 0); stageA(j + 1, 1);
            stageB(j + 1, 0); stageB(j + 1, 1);
        }
        // reads + MFMAs of tile j — free-running, compiler-scheduled
        RD_BV(buf);
        RD_AQ(buf, 0);
        MMA(0);
        RD_AQ(buf, 1);
        MMA(1);
        RD_AQ(buf, 2);
        MMA(2);
        RD_AQ(buf, 3);
        MMA(3);
    }
    #undef RD_BV
    #undef RD_AQ
    #undef MMA

    // ---- epilogue: row = wm*128 + a*16 + l4*4, col per fragment ----
    #pragma unroll
    for (int a = 0; a < 8; ++a) {
        const int row0 = m0 + wm * 128 + a * 16 + l4 * 4;
        #pragma unroll
        for (int nf = 0; nf < 4; ++nf) {
            const int col = n0 + wn * 64 + nf * 16 + l15;
            const float badd = bias[col];
            float* cp = C + (size_t)row0 * DOUT + col;
            #pragma unroll
            for (int q = 0; q < 4; ++q)
                cp[(size_t)q * DOUT] = acc[a][nf][q] + badd;
        }
    }
}

// ---------------------------------------------------------------------------
extern "C" void kernel_launch(void* const* d_in, const int* in_sizes, int n_in,
                              void* d_out, int out_size, void* d_ws, size_t ws_size,
                              hipStream_t stream)
{
    const float* x    = (const float*)d_in[0];
    const float* gw   = (const float*)d_in[1];
    const float* gb   = (const float*)d_in[2];
    const float* W    = (const float*)d_in[3];
    const float* bias = (const float*)d_in[4];
    const float* la   = (const float*)d_in[5];
    const float* lb   = (const float*)d_in[6];
    float* out = (float*)d_out;

    char* ws = (char*)d_ws;
    u16*   Xb   = (u16*)(ws);                       // 37,748,736 B
    u16*   Waug = (u16*)(ws + 37748736);            //  9,437,184 B
    float* P    = (float*)(ws + 47185920);          //  1,048,576 B
    u16*   LAb  = (u16*)(ws + 48234496);            //    262,144 B
    float* G    = (float*)(ws + 48496640);          //        256 B

    k1_reduce_convert<<<dim3(BDIM, SCH), 256, 0, stream>>>(x, Xb, P);
    kw_build_waug<<<DOUT, 256, 0, stream>>>(W, lb, Waug);
    kl_convert<<<(EDIM * RDIM * DIN + 255) / 256, 256, 0, stream>>>(la, LAb);
    k2_gates<<<dim3(EDIM, BDIM), 256, 0, stream>>>(P, gw, gb, G);
    gemm_lora<<<dim3(1, MDIM / 128), 256, 0, stream>>>(Xb, LAb, G, Xb);
    gemm_main<<<dim3(DOUT / 256, MDIM / 256), 512, 0, stream>>>(
        Xb, Waug, out, bias);
}

// Round 17
// 231.369 us; speedup vs baseline: 1.1008x; 1.1008x over previous
//
#include <hip/hip_runtime.h>
#include <stdint.h>

typedef unsigned short u16;
typedef __bf16 bf16x8 __attribute__((ext_vector_type(8)));
typedef float  f32x4  __attribute__((ext_vector_type(4)));

// ---- problem constants ----
#define SDIM 2048
#define BDIM 8
#define DIN  1024
#define DOUT 4096
#define EDIM 8
#define RDIM 16
#define KAUG 1152            // DIN + E*R
#define MDIM (SDIM*BDIM)     // 16384
#define SCH  32
#define NT2  18              // K-tiles of 64 for the main GEMM

__device__ __forceinline__ u16 f2bf(float f) {
    __bf16 h = (__bf16)f;
    return __builtin_bit_cast(u16, h);
}

__device__ __forceinline__ void gload16(const u16* g, u16* lds) {
    __builtin_amdgcn_global_load_lds(
        (const __attribute__((address_space(1))) void*)g,
        (__attribute__((address_space(3))) void*)lds, 16, 0, 0);
}

#define VMCNT(n)  asm volatile("s_waitcnt vmcnt(" #n ")" ::: "memory")
#define BARF()    do { asm volatile("" ::: "memory");                \
                       __builtin_amdgcn_s_barrier();                 \
                       asm volatile("" ::: "memory"); } while (0)

// ---------------------------------------------------------------------------
// k1: per-(b, s-chunk) partial sums of x over s + bf16 convert into Xb
// ---------------------------------------------------------------------------
__global__ __launch_bounds__(256) void k1_reduce_convert(
    const float* __restrict__ x, u16* __restrict__ Xb, float* __restrict__ P)
{
    const int b  = blockIdx.x;
    const int sc = blockIdx.y;
    const int i  = threadIdx.x * 4;
    float a0 = 0.f, a1 = 0.f, a2 = 0.f, a3 = 0.f;
    const int s0 = sc * (SDIM / SCH);
    for (int s = s0; s < s0 + (SDIM / SCH); ++s) {
        const float4 v = *reinterpret_cast<const float4*>(
            &x[((size_t)s * BDIM + b) * DIN + i]);
        a0 += v.x; a1 += v.y; a2 += v.z; a3 += v.w;
        ushort4 u{f2bf(v.x), f2bf(v.y), f2bf(v.z), f2bf(v.w)};
        *reinterpret_cast<ushort4*>(&Xb[((size_t)s * BDIM + b) * KAUG + i]) = u;
    }
    float4 p{a0, a1, a2, a3};
    *reinterpret_cast<float4*>(&P[((size_t)sc * BDIM + b) * DIN + i]) = p;
}

// ---------------------------------------------------------------------------
// k2: gate weights
// ---------------------------------------------------------------------------
__global__ __launch_bounds__(256) void k2_gates(
    const float* __restrict__ P, const float* __restrict__ gw,
    const float* __restrict__ gb, float* __restrict__ g)
{
    const int e = blockIdx.x, b = blockIdx.y, t = threadIdx.x;
    float dot = 0.f;
    for (int i = t; i < DIN; i += 256) {
        float xs = 0.f;
        #pragma unroll
        for (int c = 0; c < SCH; ++c) xs += P[((size_t)c * BDIM + b) * DIN + i];
        dot += xs * gw[(size_t)e * DIN + i];
    }
    __shared__ float red[256];
    red[t] = dot;
    __syncthreads();
    #pragma unroll
    for (int off = 128; off > 0; off >>= 1) {
        if (t < off) red[t] += red[t + off];
        __syncthreads();
    }
    if (t == 0) g[b * EDIM + e] = red[0] * (1.0f / SDIM) + gb[e];
}

// ---------------------------------------------------------------------------
// kwkl: fused Waug build + lora_A convert (one launch).
//   blocks [0, DOUT): Waug row o  |  blocks [DOUT, DOUT+512): LAb chunk
// ---------------------------------------------------------------------------
__global__ __launch_bounds__(256) void kwkl_build(
    const float* __restrict__ W, const float* __restrict__ lb,
    const float* __restrict__ la, u16* __restrict__ Waug, u16* __restrict__ LAb)
{
    const int bidx = blockIdx.x, t = threadIdx.x;
    if (bidx < DOUT) {
        const int o = bidx;
        for (int i = t; i < DIN; i += 256)
            Waug[(size_t)o * KAUG + i] = f2bf(W[(size_t)o * DIN + i]);
        if (t < EDIM * RDIM) {
            const int e = t >> 4, r = t & 15;
            Waug[(size_t)o * KAUG + DIN + t] =
                f2bf(lb[((size_t)e * DOUT + o) * RDIM + r]);
        }
    } else {
        const int idx = (bidx - DOUT) * 256 + t;
        if (idx < EDIM * RDIM * DIN) LAb[idx] = f2bf(la[idx]);
    }
}

// ---------------------------------------------------------------------------
// gemm_lora2: t = Xb(:, :1024) * LAb^T with fused u = bf16(g*t) epilogue
// written into Xb cols [1024,1152). R16: tile M=64 x N=128, grid 256 blocks
// (2x CU utilization vs the old 128-block version), 256 thr / 4 waves
// (2M x 2N, per-wave 32x64, acc[2][4]). R6 coalesced+XOR LDS layout.
// LDS: As 64x64 (8KB) + Bs 128x64 (16KB) = 24KB -> multiple blocks/CU.
// Reads cols <1024 of Xb, writes cols >=1024: disjoint, no race.
// g-index: row = by*64 + wr*32 + mi*16 + l4*4 + r; all terms but l4*4+r are
// ==0 mod 8 -> (row&7) = (l4*4+r)&7 spans b=0..7 as before.
// ---------------------------------------------------------------------------
__global__ __launch_bounds__(256) void gemm_lora2(
    const u16* __restrict__ A, const u16* __restrict__ B,
    const float* __restrict__ G, u16* __restrict__ Xb)
{
    __shared__ __align__(16) u16 As[64][64];     // 8 KB
    __shared__ __align__(16) u16 Bs[128][64];    // 16 KB

    const int tid  = threadIdx.x;
    const int lane = tid & 63;
    const int l15  = lane & 15;
    const int l4   = lane >> 4;
    const int sw   = lane & 7;
    const int wid  = tid >> 6;      // 0..3
    const int wr   = wid >> 1;      // 0..1 (32-row slice)
    const int wc   = wid & 1;       // 0..1 (64-col slice)
    const int m0 = blockIdx.y * 64;

    f32x4 acc[2][4] = {};

    for (int kt = 0; kt < DIN / 64; ++kt) {
        // stage A (64 rows): 512 entries, 2/thread
        #pragma unroll
        for (int ii = 0; ii < 2; ++ii) {
            const int cix = ii * 256 + tid;
            const int row = cix >> 3, cl = cix & 7;
            const int kof = kt * 64 + ((cl ^ (row & 7)) << 3);
            gload16(A + (size_t)(m0 + row) * KAUG + kof, &As[0][0] + cix * 8);
        }
        // stage B (128 rows): 1024 entries, 4/thread
        #pragma unroll
        for (int ii = 0; ii < 4; ++ii) {
            const int cix = ii * 256 + tid;
            const int row = cix >> 3, cl = cix & 7;
            const int kof = kt * 64 + ((cl ^ (row & 7)) << 3);
            gload16(B + (size_t)row * DIN + kof, &Bs[0][0] + cix * 8);
        }
        __syncthreads();
        #pragma unroll
        for (int ks = 0; ks < 2; ++ks) {
            bf16x8 av[2], bv[4];
            #pragma unroll
            for (int mi = 0; mi < 2; ++mi)
                av[mi] = *reinterpret_cast<const bf16x8*>(
                    &As[wr * 32 + mi * 16 + l15][((ks * 4 + l4) ^ sw) << 3]);
            #pragma unroll
            for (int ni = 0; ni < 4; ++ni)
                bv[ni] = *reinterpret_cast<const bf16x8*>(
                    &Bs[wc * 64 + ni * 16 + l15][((ks * 4 + l4) ^ sw) << 3]);
            #pragma unroll
            for (int mi = 0; mi < 2; ++mi)
                #pragma unroll
                for (int ni = 0; ni < 4; ++ni)
                    acc[mi][ni] = __builtin_amdgcn_mfma_f32_16x16x32_bf16(
                        av[mi], bv[ni], acc[mi][ni], 0, 0, 0);
        }
        __syncthreads();
    }

    // fused epilogue: u = bf16(g[row&7, e] * acc) -> Xb[row][1024+col]
    #pragma unroll
    for (int mi = 0; mi < 2; ++mi) {
        const int r0 = m0 + wr * 32 + mi * 16 + l4 * 4;
        #pragma unroll
        for (int ni = 0; ni < 4; ++ni) {
            const int col = wc * 64 + ni * 16 + l15;   // 0..127
            const int e   = col >> 4;
            #pragma unroll
            for (int r = 0; r < 4; ++r) {
                const int row = r0 + r;
                const float gv = G[((row & 7) << 3) + e];
                Xb[(size_t)row * KAUG + DIN + col] = f2bf(gv * acc[mi][ni][r]);
            }
        }
    }
}

// ---------------------------------------------------------------------------
// gemm_main (R12 config, best measured: 170 us, 909 TF): R8 4-phase
// 1-barrier counted-vmcnt schedule + coalesced staging + (row&7) chunk-XOR
// swizzle + supertile XCD mapping (FETCH 166->110 MB).
// BM=BN=256, BK=64, NT2=18, 512 thr (8 waves 2Mx4N), dbuf LDS 128 KiB.
// Stage unit = half-tile (2 gloads/thread); units u%4:{A0,A1,B0,B1},
// buf=(u>>2)&1; one unit per phase, lead 5 (su = 4j+5+P).
// vmcnt ledger: at p3 of tile j issued through unit 4j+8; VMCNT(2) leaves
// unit 4j+8 in flight, confirms tile j+1. Tail: VMCNT(0) at j>=NT2-2.
// Frozen: R9/R10/R13/R14/R15 variants all measured 170-194 (this is best).
// ---------------------------------------------------------------------------
__global__ __launch_bounds__(512) void gemm_main(
    const u16* __restrict__ A, const u16* __restrict__ Bm,
    float* __restrict__ C, const float* __restrict__ bias)
{
    __shared__ __align__(16) u16 As[2][2][128][64];   // [buf][Mhalf][row][k] 64 KiB
    __shared__ __align__(16) u16 Bs[2][2][128][64];   // [buf][Nhalf][row][k] 64 KiB

    const int tid  = threadIdx.x;
    const int lane = tid & 63;
    const int l15  = lane & 15;
    const int l4   = lane >> 4;
    const int sw   = lane & 7;
    const int wid  = tid >> 6;      // 0..7
    const int wm   = wid >> 2;      // 0..1  (128-row half)
    const int wn   = wid & 3;       // 0..3  (64-col quarter)
    const int bh   = wn >> 1;       // B Nhalf
    const int bl   = wn & 1;        // 64-row block within half

    // supertile XCD mapping (R12-verified)
    const int f   = blockIdx.x + blockIdx.y * gridDim.x;
    const int xcd = f & 7, k = f >> 3;
    const int gn  = xcd & 3, gm = xcd >> 2;
    const int n0  = (gn * 4 + (k & 3)) * 256;
    const int m0  = (gm * 32 + (k >> 2)) * 256;

    f32x4  acc[8][4] = {};
    bf16x8 aq[2][2], bv[4][2];

    auto stage = [&](int s) {
        const int t = s >> 2, part = s & 3, buf = t & 1, hf = part & 1;
        #pragma unroll
        for (int ii = 0; ii < 2; ++ii) {
            const int cix = ii * 512 + tid;
            const int row = cix >> 3, cl = cix & 7;
            const int kof = t * 64 + ((cl ^ (row & 7)) << 3);
            if (part < 2)
                gload16(A + (size_t)(m0 + hf * 128 + row) * KAUG + kof,
                        &As[buf][hf][0][0] + cix * 8);
            else
                gload16(Bm + (size_t)(n0 + hf * 128 + row) * KAUG + kof,
                        &Bs[buf][hf][0][0] + cix * 8);
        }
    };

    // prologue: units 0..4 (tile 0 fully + A-h0 of tile 1) = 10 gloads
    stage(0); stage(1); stage(2); stage(3); stage(4);
    VMCNT(2);                       // confirm units 0..3 (tile 0); unit 4 in flight
    BARF();

    #define PHASE(P)                                                            \
    do {                                                                        \
        if ((P) == 0) {                                                         \
            _Pragma("unroll") for (int nf = 0; nf < 4; ++nf)                    \
                _Pragma("unroll") for (int kk = 0; kk < 2; ++kk)                \
                    bv[nf][kk] = *reinterpret_cast<const bf16x8*>(              \
                        &Bs[buf][bh][bl * 64 + nf * 16 + l15]                   \
                           [((kk * 4 + l4) ^ sw) << 3]);                        \
        }                                                                       \
        _Pragma("unroll") for (int fr = 0; fr < 2; ++fr)                        \
            _Pragma("unroll") for (int kk = 0; kk < 2; ++kk)                    \
                aq[fr][kk] = *reinterpret_cast<const bf16x8*>(                  \
                    &As[buf][wm][(P) * 32 + fr * 16 + l15]                      \
                       [((kk * 4 + l4) ^ sw) << 3]);                            \
        { const int su = 4 * j + 5 + (P); if (su < 4 * NT2) stage(su); }        \
        __builtin_amdgcn_s_setprio(1);                                          \
        _Pragma("unroll") for (int kk = 0; kk < 2; ++kk)                        \
            _Pragma("unroll") for (int fr = 0; fr < 2; ++fr)                    \
                _Pragma("unroll") for (int nf = 0; nf < 4; ++nf)                \
                    acc[(P) * 2 + fr][nf] =                                     \
                        __builtin_amdgcn_mfma_f32_16x16x32_bf16(                \
                            aq[fr][kk], bv[nf][kk], acc[(P) * 2 + fr][nf],      \
                            0, 0, 0);                                           \
        __builtin_amdgcn_s_setprio(0);                                          \
        if ((P) == 3) { if (j < NT2 - 2) VMCNT(2); else VMCNT(0); }             \
        BARF();                                                                 \
    } while (0)

    for (int j = 0; j < NT2; ++j) {
        const int buf = j & 1;
        PHASE(0);
        PHASE(1);
        PHASE(2);
        PHASE(3);
    }
    #undef PHASE

    // ---- epilogue: row = wm*128 + a*16 + l4*4, col per fragment ----
    #pragma unroll
    for (int a = 0; a < 8; ++a) {
        const int row0 = m0 + wm * 128 + a * 16 + l4 * 4;
        #pragma unroll
        for (int nf = 0; nf < 4; ++nf) {
            const int col = n0 + wn * 64 + nf * 16 + l15;
            const float badd = bias[col];
            float* cp = C + (size_t)row0 * DOUT + col;
            #pragma unroll
            for (int q = 0; q < 4; ++q)
                cp[(size_t)q * DOUT] = acc[a][nf][q] + badd;
        }
    }
}

// ---------------------------------------------------------------------------
extern "C" void kernel_launch(void* const* d_in, const int* in_sizes, int n_in,
                              void* d_out, int out_size, void* d_ws, size_t ws_size,
                              hipStream_t stream)
{
    const float* x    = (const float*)d_in[0];
    const float* gw   = (const float*)d_in[1];
    const float* gb   = (const float*)d_in[2];
    const float* W    = (const float*)d_in[3];
    const float* bias = (const float*)d_in[4];
    const float* la   = (const float*)d_in[5];
    const float* lb   = (const float*)d_in[6];
    float* out = (float*)d_out;

    char* ws = (char*)d_ws;
    u16*   Xb   = (u16*)(ws);                       // 37,748,736 B
    u16*   Waug = (u16*)(ws + 37748736);            //  9,437,184 B
    float* P    = (float*)(ws + 47185920);          //  1,048,576 B
    u16*   LAb  = (u16*)(ws + 48234496);            //    262,144 B
    float* G    = (float*)(ws + 48496640);          //        256 B

    k1_reduce_convert<<<dim3(BDIM, SCH), 256, 0, stream>>>(x, Xb, P);
    kwkl_build<<<DOUT + (EDIM * RDIM * DIN + 255) / 256, 256, 0, stream>>>(
        W, lb, la, Waug, LAb);
    k2_gates<<<dim3(EDIM, BDIM), 256, 0, stream>>>(P, gw, gb, G);
    gemm_lora2<<<dim3(1, MDIM / 64), 256, 0, stream>>>(Xb, LAb, G, Xb);
    gemm_main<<<dim3(DOUT / 256, MDIM / 256), 512, 0, stream>>>(
        Xb, Waug, out, bias);
}